// Round 3
// baseline (138.757 us; speedup 1.0000x reference)
//
#include <hip/hip_runtime.h>

#define HH 480
#define WW 640
#define NPIX (HH * WW)
#define BB 16
#define PPT 8                       // pixels per thread
#define BLK 256
#define TILES (NPIX / (BLK * PPT))  // 150 tiles per (b,pass) pair
#define NPART (TILES * BB * 2)      // 4800 block partials

__global__ __launch_bounds__(BLK) void proj_depth_loss_kernel(
    const float* __restrict__ depth0, const float* __restrict__ depth1,
    const float* __restrict__ R0, const float* __restrict__ t0,
    const float* __restrict__ R1, const float* __restrict__ t1,
    const float* __restrict__ Km, const float* __restrict__ ray,
    float* __restrict__ ws)
{
    // XCD-locality swizzle: blockIdx % 8 ~ XCD (round-robin heuristic).
    // Give each XCD 4 consecutive (b,pass) pairs so its L2 holds ~2 images.
    const int flat = blockIdx.x;
    const int xcd = flat & 7;
    const int j = flat >> 3;            // 0..599
    const int pair_local = j / TILES;   // 0..3
    const int tile = j - pair_local * TILES;
    const int pair = xcd * 4 + pair_local;  // 0..31
    const int pass = pair >> 4;
    const int b = pair & 15;

    const float* Ds = (pass == 0) ? depth0 : depth1;
    const float* Dt = (pass == 0) ? depth1 : depth0;
    const float* Ra = (pass == 0) ? R0 : R1;
    const float* ta = (pass == 0) ? t0 : t1;
    const float* Rb = (pass == 0) ? R1 : R0;
    const float* tb = (pass == 0) ? t1 : t0;

    // Per-block uniform fold: uvd = d * (M r) + c,
    // M = K * Rb * Ra^T,  c = K * (tb - Rb * Ra^T * ta)
    const float* A = Ra + b * 9;
    const float* Bm = Rb + b * 9;
    float N_[9];  // N = Rb * Ra^T : N[i][j] = sum_k Bm[i*3+k]*A[j*3+k]
    #pragma unroll
    for (int i = 0; i < 3; ++i)
        #pragma unroll
        for (int jj = 0; jj < 3; ++jj)
            N_[i*3+jj] = Bm[i*3+0]*A[jj*3+0] + Bm[i*3+1]*A[jj*3+1] + Bm[i*3+2]*A[jj*3+2];
    float tax=ta[b*3+0], tay=ta[b*3+1], taz=ta[b*3+2];
    float tbx=tb[b*3+0], tby=tb[b*3+1], tbz=tb[b*3+2];
    // q = tb - N*ta
    float qx = tbx - (N_[0]*tax + N_[1]*tay + N_[2]*taz);
    float qy = tby - (N_[3]*tax + N_[4]*tay + N_[5]*taz);
    float qz = tbz - (N_[6]*tax + N_[7]*tay + N_[8]*taz);
    float M_[9], cx, cy, cz;
    #pragma unroll
    for (int i = 0; i < 3; ++i)
        #pragma unroll
        for (int jj = 0; jj < 3; ++jj)
            M_[i*3+jj] = Km[i*3+0]*N_[0*3+jj] + Km[i*3+1]*N_[1*3+jj] + Km[i*3+2]*N_[2*3+jj];
    cx = Km[0]*qx + Km[1]*qy + Km[2]*qz;
    cy = Km[3]*qx + Km[4]*qy + Km[5]*qz;
    cz = Km[6]*qx + Km[7]*qy + Km[8]*qz;

    const float cwf = (float)WW / (float)(WW - 1);
    const float chf = (float)HH / (float)(HH - 1);

    const int n0 = tile * (BLK * PPT) + threadIdx.x * PPT;

    // vector loads: depth (8 floats), ray (24 floats)
    const float4* dp = (const float4*)(Ds + b * NPIX + n0);
    float4 da = dp[0], db_ = dp[1];
    const float4* rp = (const float4*)(ray + 3 * n0);
    float4 r0 = rp[0], r1 = rp[1], r2 = rp[2], r3 = rp[3], r4 = rp[4], r5 = rp[5];

    float dd[PPT] = {da.x, da.y, da.z, da.w, db_.x, db_.y, db_.z, db_.w};
    float rx[PPT] = {r0.x, r0.w, r1.z, r2.y, r3.x, r3.w, r4.z, r5.y};
    float ry[PPT] = {r0.y, r1.x, r1.w, r2.z, r3.y, r4.x, r4.w, r5.z};
    float rz[PPT] = {r0.z, r1.y, r2.x, r2.w, r3.z, r4.y, r5.x, r5.w};

    float ud[PPT], wxf[PPT], wyf[PPT];
    int i00[PPT], i01[PPT], i10[PPT], i11[PPT];

    #pragma unroll
    for (int i = 0; i < PPT; ++i) {
        float mrx = M_[0]*rx[i] + M_[1]*ry[i] + M_[2]*rz[i];
        float mry = M_[3]*rx[i] + M_[4]*ry[i] + M_[5]*rz[i];
        float mrz = M_[6]*rx[i] + M_[7]*ry[i] + M_[8]*rz[i];
        float ux = dd[i]*mrx + cx;
        float uy = dd[i]*mry + cy;
        float uu = dd[i]*mrz + cz;
        ud[i] = uu;

        float inv = __builtin_amdgcn_rcpf(fmaxf(uu, 0.0f) + 1e-12f);
        float sx = ux * inv * cwf - 0.5f;
        float sy = uy * inv * chf - 0.5f;
        sx = fminf(fmaxf(sx, 0.0f), (float)(WW - 1));
        sy = fminf(fmaxf(sy, 0.0f), (float)(HH - 1));
        float fx0 = floorf(sx);
        float fy0 = floorf(sy);
        wxf[i] = sx - fx0;
        wyf[i] = sy - fy0;
        int x0 = (int)fx0;
        int y0 = (int)fy0;
        int x1 = min(x0 + 1, WW - 1);
        int y1 = min(y0 + 1, HH - 1);
        i00[i] = y0 * WW + x0;
        i01[i] = y0 * WW + x1;
        i10[i] = y1 * WW + x0;
        i11[i] = y1 * WW + x1;
    }

    const float* img = Dt + b * NPIX;
    float v00[PPT], v01[PPT], v10[PPT], v11[PPT];
    #pragma unroll
    for (int i = 0; i < PPT; ++i) {
        v00[i] = img[i00[i]];
        v01[i] = img[i01[i]];
        v10[i] = img[i10[i]];
        v11[i] = img[i11[i]];
    }

    float diff = 0.0f;
    #pragma unroll
    for (int i = 0; i < PPT; ++i) {
        float top = (1.0f - wxf[i]) * v00[i] + wxf[i] * v01[i];
        float bot = (1.0f - wxf[i]) * v10[i] + wxf[i] * v11[i];
        float s = (1.0f - wyf[i]) * top + wyf[i] * bot;
        diff += fabsf(ud[i] - s);
    }

    for (int off = 32; off > 0; off >>= 1)
        diff += __shfl_down(diff, off, 64);

    __shared__ float partial[BLK / 64];
    const int wave = threadIdx.x >> 6;
    const int lane = threadIdx.x & 63;
    if (lane == 0) partial[wave] = diff;
    __syncthreads();
    if (threadIdx.x == 0) {
        float s = partial[0] + partial[1] + partial[2] + partial[3];
        ws[flat] = s;
    }
}

__global__ __launch_bounds__(1024) void reduce_partials_kernel(
    const float* __restrict__ ws, float* __restrict__ out)
{
    float s = 0.0f;
    for (int i = threadIdx.x; i < NPART; i += 1024) s += ws[i];
    for (int off = 32; off > 0; off >>= 1)
        s += __shfl_down(s, off, 64);
    __shared__ float partial[16];
    const int wave = threadIdx.x >> 6;
    const int lane = threadIdx.x & 63;
    if (lane == 0) partial[wave] = s;
    __syncthreads();
    if (threadIdx.x == 0) {
        float tot = 0.0f;
        #pragma unroll
        for (int i = 0; i < 16; ++i) tot += partial[i];
        out[0] = tot * (1.0f / (float)((long long)BB * NPIX));
    }
}

extern "C" void kernel_launch(void* const* d_in, const int* in_sizes, int n_in,
                              void* d_out, int out_size, void* d_ws, size_t ws_size,
                              hipStream_t stream) {
    const float* depth0 = (const float*)d_in[0];
    const float* depth1 = (const float*)d_in[1];
    const float* R0     = (const float*)d_in[2];
    const float* t0     = (const float*)d_in[3];
    const float* R1     = (const float*)d_in[4];
    const float* t1     = (const float*)d_in[5];
    const float* Km     = (const float*)d_in[6];
    const float* ray    = (const float*)d_in[7];
    float* out = (float*)d_out;
    float* ws  = (float*)d_ws;

    proj_depth_loss_kernel<<<dim3(NPART), dim3(BLK), 0, stream>>>(
        depth0, depth1, R0, t0, R1, t1, Km, ray, ws);
    reduce_partials_kernel<<<1, 1024, 0, stream>>>(ws, out);
}

// Round 4
// 121.434 us; speedup vs baseline: 1.1427x; 1.1427x over previous
//
#include <hip/hip_runtime.h>

#define HH 480
#define WW 640
#define NPIX (HH * WW)
#define BB 16
#define PPT 4                      // pixels per thread
#define BLK 256
#define GX (NPIX / (BLK * PPT))    // 300 blocks along pixel dim
#define NPART (GX * BB * 2)        // 9600 block partials

__global__ __launch_bounds__(BLK) void proj_depth_loss_kernel(
    const float* __restrict__ depth0, const float* __restrict__ depth1,
    const float* __restrict__ R0, const float* __restrict__ t0,
    const float* __restrict__ R1, const float* __restrict__ t1,
    const float* __restrict__ Km, const float* __restrict__ ray,
    float* __restrict__ ws)
{
    const int pass = blockIdx.z;
    const int b = blockIdx.y;
    const int n0 = (blockIdx.x * BLK + threadIdx.x) * PPT;

    const float* Ds = (pass == 0) ? depth0 : depth1;
    const float* Dt = (pass == 0) ? depth1 : depth0;
    const float* Ra = (pass == 0) ? R0 : R1;
    const float* ta = (pass == 0) ? t0 : t1;
    const float* Rb = (pass == 0) ? R1 : R0;
    const float* tb = (pass == 0) ? t1 : t0;

    // Per-block uniform fold: uvd = d * (M r) + c,
    // M = K * Rb * Ra^T,  c = K * (tb - Rb * Ra^T * ta).
    // b,pass are block-uniform -> these are scalar ops, once per block.
    const float* A = Ra + b * 9;
    const float* Bm = Rb + b * 9;
    float N_[9];  // N = Rb * Ra^T
    #pragma unroll
    for (int i = 0; i < 3; ++i)
        #pragma unroll
        for (int jj = 0; jj < 3; ++jj)
            N_[i*3+jj] = Bm[i*3+0]*A[jj*3+0] + Bm[i*3+1]*A[jj*3+1] + Bm[i*3+2]*A[jj*3+2];
    float tax=ta[b*3+0], tay=ta[b*3+1], taz=ta[b*3+2];
    float qx = tb[b*3+0] - (N_[0]*tax + N_[1]*tay + N_[2]*taz);
    float qy = tb[b*3+1] - (N_[3]*tax + N_[4]*tay + N_[5]*taz);
    float qz = tb[b*3+2] - (N_[6]*tax + N_[7]*tay + N_[8]*taz);
    float M_[9];
    #pragma unroll
    for (int i = 0; i < 3; ++i)
        #pragma unroll
        for (int jj = 0; jj < 3; ++jj)
            M_[i*3+jj] = Km[i*3+0]*N_[0*3+jj] + Km[i*3+1]*N_[1*3+jj] + Km[i*3+2]*N_[2*3+jj];
    float cx = Km[0]*qx + Km[1]*qy + Km[2]*qz;
    float cy = Km[3]*qx + Km[4]*qy + Km[5]*qz;
    float cz = Km[6]*qx + Km[7]*qy + Km[8]*qz;

    const float cwf = (float)WW / (float)(WW - 1);
    const float chf = (float)HH / (float)(HH - 1);

    // vector loads: depth (4 floats), ray (12 floats)
    float4 d4 = *(const float4*)(Ds + b * NPIX + n0);
    const float4* rp = (const float4*)(ray + 3 * n0);
    float4 r0 = rp[0], r1 = rp[1], r2 = rp[2];

    float dd[PPT] = {d4.x, d4.y, d4.z, d4.w};
    float rx[PPT] = {r0.x, r0.w, r1.z, r2.y};
    float ry[PPT] = {r0.y, r1.x, r1.w, r2.z};
    float rz[PPT] = {r0.z, r1.y, r2.x, r2.w};

    float ud[PPT], wxf[PPT], wyf[PPT];
    int i00[PPT], dx1[PPT], dy1[PPT];

    #pragma unroll
    for (int i = 0; i < PPT; ++i) {
        float mrx = M_[0]*rx[i] + M_[1]*ry[i] + M_[2]*rz[i];
        float mry = M_[3]*rx[i] + M_[4]*ry[i] + M_[5]*rz[i];
        float mrz = M_[6]*rx[i] + M_[7]*ry[i] + M_[8]*rz[i];
        float ux = dd[i]*mrx + cx;
        float uy = dd[i]*mry + cy;
        float uu = dd[i]*mrz + cz;
        ud[i] = uu;

        float inv = __builtin_amdgcn_rcpf(fmaxf(uu, 0.0f) + 1e-12f);
        float sx = ux * inv * cwf - 0.5f;
        float sy = uy * inv * chf - 0.5f;
        sx = fminf(fmaxf(sx, 0.0f), (float)(WW - 1));
        sy = fminf(fmaxf(sy, 0.0f), (float)(HH - 1));
        float fx0 = floorf(sx);
        float fy0 = floorf(sy);
        wxf[i] = sx - fx0;
        wyf[i] = sy - fy0;
        int x0 = (int)fx0;
        int y0 = (int)fy0;
        i00[i] = y0 * WW + x0;
        dx1[i] = (x0 < WW - 1) ? 1 : 0;
        dy1[i] = (y0 < HH - 1) ? WW : 0;
    }

    const float* img = Dt + b * NPIX;
    float v00[PPT], v01[PPT], v10[PPT], v11[PPT];
    #pragma unroll
    for (int i = 0; i < PPT; ++i) {
        v00[i] = img[i00[i]];
        v01[i] = img[i00[i] + dx1[i]];
        v10[i] = img[i00[i] + dy1[i]];
        v11[i] = img[i00[i] + dy1[i] + dx1[i]];
    }

    float diff = 0.0f;
    #pragma unroll
    for (int i = 0; i < PPT; ++i) {
        float top = v00[i] + wxf[i] * (v01[i] - v00[i]);
        float bot = v10[i] + wxf[i] * (v11[i] - v10[i]);
        float s = top + wyf[i] * (bot - top);
        diff += fabsf(ud[i] - s);
    }

    for (int off = 32; off > 0; off >>= 1)
        diff += __shfl_down(diff, off, 64);

    __shared__ float partial[BLK / 64];
    const int wave = threadIdx.x >> 6;
    const int lane = threadIdx.x & 63;
    if (lane == 0) partial[wave] = diff;
    __syncthreads();
    if (threadIdx.x == 0) {
        float s = partial[0] + partial[1] + partial[2] + partial[3];
        ws[blockIdx.x + GX * (blockIdx.y + BB * blockIdx.z)] = s;
    }
}

__global__ __launch_bounds__(1024) void reduce_partials_kernel(
    const float* __restrict__ ws, float* __restrict__ out)
{
    float s = 0.0f;
    for (int i = threadIdx.x; i < NPART; i += 1024) s += ws[i];
    for (int off = 32; off > 0; off >>= 1)
        s += __shfl_down(s, off, 64);
    __shared__ float partial[16];
    const int wave = threadIdx.x >> 6;
    const int lane = threadIdx.x & 63;
    if (lane == 0) partial[wave] = s;
    __syncthreads();
    if (threadIdx.x == 0) {
        float tot = 0.0f;
        #pragma unroll
        for (int i = 0; i < 16; ++i) tot += partial[i];
        out[0] = tot * (1.0f / (float)((long long)BB * NPIX));
    }
}

extern "C" void kernel_launch(void* const* d_in, const int* in_sizes, int n_in,
                              void* d_out, int out_size, void* d_ws, size_t ws_size,
                              hipStream_t stream) {
    const float* depth0 = (const float*)d_in[0];
    const float* depth1 = (const float*)d_in[1];
    const float* R0     = (const float*)d_in[2];
    const float* t0     = (const float*)d_in[3];
    const float* R1     = (const float*)d_in[4];
    const float* t1     = (const float*)d_in[5];
    const float* Km     = (const float*)d_in[6];
    const float* ray    = (const float*)d_in[7];
    float* out = (float*)d_out;
    float* ws  = (float*)d_ws;

    dim3 block(BLK);
    dim3 grid(GX, BB, 2);
    proj_depth_loss_kernel<<<grid, block, 0, stream>>>(
        depth0, depth1, R0, t0, R1, t1, Km, ray, ws);
    reduce_partials_kernel<<<1, 1024, 0, stream>>>(ws, out);
}

// Round 5
// 115.610 us; speedup vs baseline: 1.2002x; 1.0504x over previous
//
#include <hip/hip_runtime.h>

#define HH 480
#define WW 640
#define NPIX (HH * WW)
#define BB 16
#define PPT 4                      // pixels per thread
#define BLK 256
#define GX (NPIX / (BLK * PPT))    // 300 blocks along pixel dim
#define NPART (GX * BB * 2)        // 9600 block partials

typedef float vf2 __attribute__((ext_vector_type(2)));
struct __attribute__((packed, aligned(4))) uf2 { vf2 v; };

__global__ __launch_bounds__(BLK) void proj_depth_loss_kernel(
    const float* __restrict__ depth0, const float* __restrict__ depth1,
    const float* __restrict__ R0, const float* __restrict__ t0,
    const float* __restrict__ R1, const float* __restrict__ t1,
    const float* __restrict__ Km, const float* __restrict__ ray,
    float* __restrict__ ws)
{
    const int pass = blockIdx.z;
    const int b = blockIdx.y;
    const int n0 = (blockIdx.x * BLK + threadIdx.x) * PPT;

    const float* Ds = (pass == 0) ? depth0 : depth1;
    const float* Dt = (pass == 0) ? depth1 : depth0;
    const float* Ra = (pass == 0) ? R0 : R1;
    const float* ta = (pass == 0) ? t0 : t1;
    const float* Rb = (pass == 0) ? R1 : R0;
    const float* tb = (pass == 0) ? t1 : t0;

    // Per-block uniform fold: uvd = d * (M r) + c,
    // M = K * Rb * Ra^T,  c = K * (tb - Rb * Ra^T * ta).
    const float* A = Ra + b * 9;
    const float* Bm = Rb + b * 9;
    float N_[9];  // N = Rb * Ra^T
    #pragma unroll
    for (int i = 0; i < 3; ++i)
        #pragma unroll
        for (int jj = 0; jj < 3; ++jj)
            N_[i*3+jj] = Bm[i*3+0]*A[jj*3+0] + Bm[i*3+1]*A[jj*3+1] + Bm[i*3+2]*A[jj*3+2];
    float tax=ta[b*3+0], tay=ta[b*3+1], taz=ta[b*3+2];
    float qx = tb[b*3+0] - (N_[0]*tax + N_[1]*tay + N_[2]*taz);
    float qy = tb[b*3+1] - (N_[3]*tax + N_[4]*tay + N_[5]*taz);
    float qz = tb[b*3+2] - (N_[6]*tax + N_[7]*tay + N_[8]*taz);
    float M_[9];
    #pragma unroll
    for (int i = 0; i < 3; ++i)
        #pragma unroll
        for (int jj = 0; jj < 3; ++jj)
            M_[i*3+jj] = Km[i*3+0]*N_[0*3+jj] + Km[i*3+1]*N_[1*3+jj] + Km[i*3+2]*N_[2*3+jj];
    float cx = Km[0]*qx + Km[1]*qy + Km[2]*qz;
    float cy = Km[3]*qx + Km[4]*qy + Km[5]*qz;
    float cz = Km[6]*qx + Km[7]*qy + Km[8]*qz;

    const float cwf = (float)WW / (float)(WW - 1);
    const float chf = (float)HH / (float)(HH - 1);

    // vector loads: depth (4 floats), ray (12 floats)
    float4 d4 = *(const float4*)(Ds + b * NPIX + n0);
    const float4* rp = (const float4*)(ray + 3 * n0);
    float4 r0 = rp[0], r1 = rp[1], r2 = rp[2];

    float dd[PPT] = {d4.x, d4.y, d4.z, d4.w};
    float rx[PPT] = {r0.x, r0.w, r1.z, r2.y};
    float ry[PPT] = {r0.y, r1.x, r1.w, r2.z};
    float rz[PPT] = {r0.z, r1.y, r2.x, r2.w};

    float ud[PPT], wxs[PPT], wyf[PPT];
    int base[PPT], dy1[PPT];

    #pragma unroll
    for (int i = 0; i < PPT; ++i) {
        float mrx = M_[0]*rx[i] + M_[1]*ry[i] + M_[2]*rz[i];
        float mry = M_[3]*rx[i] + M_[4]*ry[i] + M_[5]*rz[i];
        float mrz = M_[6]*rx[i] + M_[7]*ry[i] + M_[8]*rz[i];
        float ux = dd[i]*mrx + cx;
        float uy = dd[i]*mry + cy;
        float uu = dd[i]*mrz + cz;
        ud[i] = uu;

        float inv = __builtin_amdgcn_rcpf(fmaxf(uu, 0.0f) + 1e-12f);
        float sx = ux * inv * cwf - 0.5f;
        float sy = uy * inv * chf - 0.5f;
        sx = fminf(fmaxf(sx, 0.0f), (float)(WW - 1));
        sy = fminf(fmaxf(sy, 0.0f), (float)(HH - 1));
        float fx0 = floorf(sx);
        float fy0 = floorf(sy);
        float wxf = sx - fx0;
        wyf[i] = sy - fy0;
        int x0 = (int)fx0;
        int y0 = (int)fy0;
        // Pair-load trick: fetch {img[p], img[p+1]} in ONE dwordx2.
        // x0 == W-1 implies sx == W-1 exactly, so wxf == 0; shift the
        // window left by 1 and force the lerp weight to 1.0 so the
        // result is img[i00] exactly. Keeps all accesses in-bounds.
        int atEdge = (x0 == WW - 1);
        base[i] = y0 * WW + x0 - atEdge;
        wxs[i] = atEdge ? 1.0f : wxf;
        dy1[i] = (y0 < HH - 1) ? WW : 0;
    }

    const float* img = Dt + b * NPIX;
    vf2 top[PPT], bot[PPT];
    #pragma unroll
    for (int i = 0; i < PPT; ++i) {
        top[i] = ((const uf2*)(img + base[i]))->v;            // {v00, v01}
        bot[i] = ((const uf2*)(img + base[i] + dy1[i]))->v;   // {v10, v11}
    }

    float diff = 0.0f;
    #pragma unroll
    for (int i = 0; i < PPT; ++i) {
        float tv = top[i].x + wxs[i] * (top[i].y - top[i].x);
        float bv = bot[i].x + wxs[i] * (bot[i].y - bot[i].x);
        float s = tv + wyf[i] * (bv - tv);
        diff += fabsf(ud[i] - s);
    }

    for (int off = 32; off > 0; off >>= 1)
        diff += __shfl_down(diff, off, 64);

    __shared__ float partial[BLK / 64];
    const int wave = threadIdx.x >> 6;
    const int lane = threadIdx.x & 63;
    if (lane == 0) partial[wave] = diff;
    __syncthreads();
    if (threadIdx.x == 0) {
        float s = partial[0] + partial[1] + partial[2] + partial[3];
        ws[blockIdx.x + GX * (blockIdx.y + BB * blockIdx.z)] = s;
    }
}

__global__ __launch_bounds__(1024) void reduce_partials_kernel(
    const float* __restrict__ ws, float* __restrict__ out)
{
    float s = 0.0f;
    for (int i = threadIdx.x; i < NPART; i += 1024) s += ws[i];
    for (int off = 32; off > 0; off >>= 1)
        s += __shfl_down(s, off, 64);
    __shared__ float partial[16];
    const int wave = threadIdx.x >> 6;
    const int lane = threadIdx.x & 63;
    if (lane == 0) partial[wave] = s;
    __syncthreads();
    if (threadIdx.x == 0) {
        float tot = 0.0f;
        #pragma unroll
        for (int i = 0; i < 16; ++i) tot += partial[i];
        out[0] = tot * (1.0f / (float)((long long)BB * NPIX));
    }
}

extern "C" void kernel_launch(void* const* d_in, const int* in_sizes, int n_in,
                              void* d_out, int out_size, void* d_ws, size_t ws_size,
                              hipStream_t stream) {
    const float* depth0 = (const float*)d_in[0];
    const float* depth1 = (const float*)d_in[1];
    const float* R0     = (const float*)d_in[2];
    const float* t0     = (const float*)d_in[3];
    const float* R1     = (const float*)d_in[4];
    const float* t1     = (const float*)d_in[5];
    const float* Km     = (const float*)d_in[6];
    const float* ray    = (const float*)d_in[7];
    float* out = (float*)d_out;
    float* ws  = (float*)d_ws;

    dim3 block(BLK);
    dim3 grid(GX, BB, 2);
    proj_depth_loss_kernel<<<grid, block, 0, stream>>>(
        depth0, depth1, R0, t0, R1, t1, Km, ray, ws);
    reduce_partials_kernel<<<1, 1024, 0, stream>>>(ws, out);
}